// Round 1
// baseline (230.684 us; speedup 1.0000x reference)
//
#include <hip/hip_runtime.h>

// LinearKoopmanLayer: out[b,2f,t]   = c*x[b,2f,t] - s*x[b,2f+1,t]
//                     out[b,2f+1,t] = s*x[b,2f,t] + c*x[b,2f+1,t]
// where a = amp[f]^dt[b], c = a*cos(freq[f]*dt[b]), s = a*sin(freq[f]*dt[b]).
// Memory-bound: 128 MiB in + 128 MiB out fp32. One block per (b,f) pair,
// 256 threads x float4 covers both T=1024 rows exactly.

constexpr int Bn = 256;
constexpr int Fn = 64;
constexpr int Tn = 1024;

__global__ __launch_bounds__(256) void koopman_kernel(
    const float* __restrict__ x,
    const float* __restrict__ delta_t,
    const float* __restrict__ amplitudes,
    const float* __restrict__ frequencies,
    float* __restrict__ out) {
    const int bf = blockIdx.x;        // 0 .. B*F-1
    const int b  = bf >> 6;           // F = 64
    const int f  = bf & 63;

    // Block-uniform coefficients (dt[b], amp[f], freq[f] depend only on blockIdx)
    const float d   = delta_t[b];
    const float a   = powf(amplitudes[f], d);
    const float ang = frequencies[f] * d;
    float s, c;
    sincosf(ang, &s, &c);
    c *= a;
    s *= a;

    // Rows 2f (x0) and 2f+1 (x1) are contiguous 1024-float stripes.
    const size_t base = (size_t)bf * (2 * Tn);
    const float4* __restrict__ x0 = reinterpret_cast<const float4*>(x + base);
    const float4* __restrict__ x1 = x0 + (Tn / 4);
    float4* __restrict__ o0 = reinterpret_cast<float4*>(out + base);
    float4* __restrict__ o1 = o0 + (Tn / 4);

    const int t = threadIdx.x;        // 0..255 == Tn/4 - 1
    const float4 v0 = x0[t];
    const float4 v1 = x1[t];

    float4 r0, r1;
    r0.x = c * v0.x - s * v1.x;  r1.x = s * v0.x + c * v1.x;
    r0.y = c * v0.y - s * v1.y;  r1.y = s * v0.y + c * v1.y;
    r0.z = c * v0.z - s * v1.z;  r1.z = s * v0.z + c * v1.z;
    r0.w = c * v0.w - s * v1.w;  r1.w = s * v0.w + c * v1.w;

    o0[t] = r0;
    o1[t] = r1;
}

extern "C" void kernel_launch(void* const* d_in, const int* in_sizes, int n_in,
                              void* d_out, int out_size, void* d_ws, size_t ws_size,
                              hipStream_t stream) {
    const float* x    = (const float*)d_in[0];
    const float* dt   = (const float*)d_in[1];
    const float* amp  = (const float*)d_in[2];
    const float* freq = (const float*)d_in[3];
    float* out = (float*)d_out;

    dim3 grid(Bn * Fn);
    dim3 block(256);
    koopman_kernel<<<grid, block, 0, stream>>>(x, dt, amp, freq, out);
}

// Round 3
// 225.571 us; speedup vs baseline: 1.0227x; 1.0227x over previous
//
#include <hip/hip_runtime.h>

// LinearKoopmanLayer: out[b,2f,t]   = c*x[b,2f,t] - s*x[b,2f+1,t]
//                     out[b,2f+1,t] = s*x[b,2f,t] + c*x[b,2f+1,t]
// a = amp[f]^dt[b], c = a*cos(freq[f]*dt[b]), s = a*sin(freq[f]*dt[b]).
//
// Two-phase: (1) tiny kernel computes all 16384 {c,s} pairs into d_ws,
// removing powf/sincosf from the 65536 streaming waves; (2) pure-stream
// rotate kernel, nontemporal 16B accesses (no reuse -> skip cache pollution).
// Note: __builtin_nontemporal_* needs a native vector type, not HIP float4.

constexpr int Bn = 256;
constexpr int Fn = 64;
constexpr int Tn = 1024;

typedef float v4f __attribute__((ext_vector_type(4)));

__global__ __launch_bounds__(64) void koopman_coef_kernel(
    const float* __restrict__ delta_t,
    const float* __restrict__ amplitudes,
    const float* __restrict__ frequencies,
    float2* __restrict__ cs) {
    const int idx = blockIdx.x * 64 + threadIdx.x;  // 0 .. B*F-1
    const int b = idx >> 6;
    const int f = idx & 63;
    const float d = delta_t[b];
    const float a = powf(amplitudes[f], d);
    float s, c;
    sincosf(frequencies[f] * d, &s, &c);
    cs[idx] = make_float2(a * c, a * s);
}

__global__ __launch_bounds__(256) void koopman_stream_kernel(
    const float* __restrict__ x,
    const float2* __restrict__ cs,
    float* __restrict__ out) {
    const int bf = blockIdx.x;           // block-uniform -> scalar load
    const float2 k = cs[bf];
    const float c = k.x, s = k.y;

    const size_t base = (size_t)bf * (2 * Tn);
    const v4f* __restrict__ x0 = reinterpret_cast<const v4f*>(x + base);
    const v4f* __restrict__ x1 = x0 + (Tn / 4);
    v4f* __restrict__ o0 = reinterpret_cast<v4f*>(out + base);
    v4f* __restrict__ o1 = o0 + (Tn / 4);

    const int t = threadIdx.x;           // 0..255 covers Tn/4
    const v4f v0 = __builtin_nontemporal_load(&x0[t]);
    const v4f v1 = __builtin_nontemporal_load(&x1[t]);

    const v4f r0 = c * v0 - s * v1;
    const v4f r1 = s * v0 + c * v1;

    __builtin_nontemporal_store(r0, &o0[t]);
    __builtin_nontemporal_store(r1, &o1[t]);
}

extern "C" void kernel_launch(void* const* d_in, const int* in_sizes, int n_in,
                              void* d_out, int out_size, void* d_ws, size_t ws_size,
                              hipStream_t stream) {
    const float* x    = (const float*)d_in[0];
    const float* dt   = (const float*)d_in[1];
    const float* amp  = (const float*)d_in[2];
    const float* freq = (const float*)d_in[3];
    float* out = (float*)d_out;
    float2* cs = (float2*)d_ws;          // 16384 * 8 B = 128 KiB scratch

    koopman_coef_kernel<<<dim3(Bn * Fn / 64), dim3(64), 0, stream>>>(dt, amp, freq, cs);
    koopman_stream_kernel<<<dim3(Bn * Fn), dim3(256), 0, stream>>>(x, cs, out);
}

// Round 5
// 223.624 us; speedup vs baseline: 1.0316x; 1.0087x over previous
//
#include <hip/hip_runtime.h>

// LinearKoopmanLayer: out[b,2f,t]   = c*x[b,2f,t] - s*x[b,2f+1,t]
//                     out[b,2f+1,t] = s*x[b,2f,t] + c*x[b,2f+1,t]
// a = amp[f]^dt[b], c = a*cos(freq[f]*dt[b]), s = a*sin(freq[f]*dt[b]).
//
// Single fused streaming kernel. Coefficients via raw AMDGCN HW
// transcendental builtins (v_log_f32 / v_exp_f32 / v_sin_f32 / v_cos_f32,
// ~8 VALU insts) — cheap enough to compute redundantly per thread: no
// separate coef kernel, no d_ws round-trip, one graph node. NOTE:
// v_sin/v_cos take input in REVOLUTIONS (x·2π), hence the 1/2π scale.
// Loads issued before coefficient math so transcendental latency hides
// under the vmcnt wait. Nontemporal 16B accesses (zero reuse).

constexpr int Bn = 256;
constexpr int Fn = 64;
constexpr int Tn = 1024;

typedef float v4f __attribute__((ext_vector_type(4)));

__global__ __launch_bounds__(256) void koopman_kernel(
    const float* __restrict__ x,
    const float* __restrict__ delta_t,
    const float* __restrict__ amplitudes,
    const float* __restrict__ frequencies,
    float* __restrict__ out) {
    const int bf = blockIdx.x;        // 0 .. B*F-1
    const int t  = threadIdx.x;       // 0..255 covers Tn/4

    // Rows 2f (x0) and 2f+1 (x1) are contiguous 1024-float stripes.
    const size_t base = (size_t)bf * (2 * Tn);
    const v4f* __restrict__ x0 = reinterpret_cast<const v4f*>(x + base);
    const v4f* __restrict__ x1 = x0 + (Tn / 4);
    v4f* __restrict__ o0 = reinterpret_cast<v4f*>(out + base);
    v4f* __restrict__ o1 = o0 + (Tn / 4);

    // Issue the streaming loads first; coefficient math overlaps the wait.
    const v4f v0 = __builtin_nontemporal_load(&x0[t]);
    const v4f v1 = __builtin_nontemporal_load(&x1[t]);

    // Block-uniform coefficients via native transcendentals.
    const int b = bf >> 6;            // F = 64
    const int f = bf & 63;
    const float d = delta_t[b];
    // amp^d = exp2(d * log2(amp)), amp in [0.7,1.3]
    const float a = __builtin_amdgcn_exp2f(d * __builtin_amdgcn_logf(amplitudes[f]));
    // v_sin/v_cos take revolutions: sin(ang) = v_sin(ang / 2pi)
    const float rev = (frequencies[f] * d) * 0.15915494309189535f;
    float s = a * __builtin_amdgcn_sinf(rev);
    float c = a * __builtin_amdgcn_cosf(rev);

    const v4f r0 = c * v0 - s * v1;
    const v4f r1 = s * v0 + c * v1;

    __builtin_nontemporal_store(r0, &o0[t]);
    __builtin_nontemporal_store(r1, &o1[t]);
}

extern "C" void kernel_launch(void* const* d_in, const int* in_sizes, int n_in,
                              void* d_out, int out_size, void* d_ws, size_t ws_size,
                              hipStream_t stream) {
    const float* x    = (const float*)d_in[0];
    const float* dt   = (const float*)d_in[1];
    const float* amp  = (const float*)d_in[2];
    const float* freq = (const float*)d_in[3];
    float* out = (float*)d_out;

    koopman_kernel<<<dim3(Bn * Fn), dim3(256), 0, stream>>>(x, dt, amp, freq, out);
}